// Round 1
// baseline (14435.338 us; speedup 1.0000x reference)
//
#include <hip/hip_runtime.h>
#include <hip/hip_bf16.h>

#define NNODES 100000
#define NPG    12500
#define NGRAPH 8
#define KD     128
#define CD     128
#define INDIM  7
#define GSDIM  11
#define NBLKS  4
#define NCLF   5
#define NEDGE  800000
#define TBSPLIT 16

// 4x4 outer-product accumulate: ACC[i][q] += E_i * S_q
#define OUTER4(ACC, E, S) do {                                              \
  ACC[0][0] = fmaf((E).x,(S).x,ACC[0][0]); ACC[0][1] = fmaf((E).x,(S).y,ACC[0][1]); \
  ACC[0][2] = fmaf((E).x,(S).z,ACC[0][2]); ACC[0][3] = fmaf((E).x,(S).w,ACC[0][3]); \
  ACC[1][0] = fmaf((E).y,(S).x,ACC[1][0]); ACC[1][1] = fmaf((E).y,(S).y,ACC[1][1]); \
  ACC[1][2] = fmaf((E).y,(S).z,ACC[1][2]); ACC[1][3] = fmaf((E).y,(S).w,ACC[1][3]); \
  ACC[2][0] = fmaf((E).z,(S).x,ACC[2][0]); ACC[2][1] = fmaf((E).z,(S).y,ACC[2][1]); \
  ACC[2][2] = fmaf((E).z,(S).z,ACC[2][2]); ACC[2][3] = fmaf((E).z,(S).w,ACC[2][3]); \
  ACC[3][0] = fmaf((E).w,(S).x,ACC[3][0]); ACC[3][1] = fmaf((E).w,(S).y,ACC[3][1]); \
  ACC[3][2] = fmaf((E).w,(S).z,ACC[3][2]); ACC[3][3] = fmaf((E).w,(S).w,ACC[3][3]); \
} while (0)

__global__ void k_fill0(float4* p, int n4) {
  int i = blockIdx.x * blockDim.x + threadIdx.x;
  int s = gridDim.x * blockDim.x;
  float4 z = make_float4(0.f, 0.f, 0.f, 0.f);
  for (; i < n4; i += s) p[i] = z;
}

// h = relu(x @ W_embed + b_embed); 2 nodes per 256-thread block
__global__ void k_embed(const float* __restrict__ x, const float* __restrict__ W,
                        const float* __restrict__ bv, float* __restrict__ h) {
  int w = threadIdx.x >> 7;
  int c = threadIdx.x & 127;
  int n = blockIdx.x * 2 + w;
  __shared__ float xs[2][INDIM];
  if (c < INDIM) xs[w][c] = x[n * INDIM + c];
  __syncthreads();
  float acc = bv[c];
#pragma unroll
  for (int i = 0; i < INDIM; ++i) acc = fmaf(xs[w][i], W[i * CD + c], acc);
  h[(size_t)n * CD + c] = fmaxf(acc, 0.f);
}

// A_T[blk][j][c] = A[blk][c][j]
__global__ void k_transA(const float* __restrict__ A, float* __restrict__ A_T) {
  int i = blockIdx.x * 256 + threadIdx.x;     // over 4*128*128
  int c = i & 127, j = (i >> 7) & 127, blk = i >> 14;
  A_T[i] = A[blk * 16384 + c * 128 + j];
}

// spec[b,k,c] += sum_n ev[b,n,k] * h[b,n,c] * mass[b,n]   (split-n + atomics)
__global__ void k_to_basis(const float* __restrict__ evecs, const float* __restrict__ h,
                           const float* __restrict__ mass, float* spec) {
  int wg = blockIdx.x;
  int b  = wg >> 6;           // 4 ktiles * 16 splits = 64 per graph
  int kt = (wg >> 4) & 3;
  int ns = wg & 15;
  int t  = threadIdx.x;
  int c  = t & 127;
  int kh = t >> 7;            // 0..1, k-halves of 16
  const int nchunk = (NPG + TBSPLIT - 1) / TBSPLIT;   // 782
  int n0 = ns * nchunk;
  int n1 = min(n0 + nchunk, NPG);
  __shared__ float hm_s[32][128];
  __shared__ float ev_s[32][32];
  float acc[16];
#pragma unroll
  for (int i = 0; i < 16; ++i) acc[i] = 0.f;
  size_t gbase = (size_t)b * NPG;
  for (int nb = n0; nb < n1; nb += 32) {
#pragma unroll
    for (int l = 0; l < 16; ++l) {
      int idx = l * 256 + t;
      int row = idx >> 7, col = idx & 127;
      int n = nb + row;
      float v = 0.f;
      if (n < n1) v = h[(gbase + n) * CD + col] * mass[gbase + n];
      hm_s[row][col] = v;
    }
#pragma unroll
    for (int l = 0; l < 4; ++l) {
      int idx = l * 256 + t;
      int row = idx >> 5, kk = idx & 31;
      int n = nb + row;
      ev_s[row][kk] = (n < n1) ? evecs[(gbase + n) * KD + kt * 32 + kk] : 0.f;
    }
    __syncthreads();
#pragma unroll
    for (int nn = 0; nn < 32; ++nn) {
      float a = hm_s[nn][c];
      const float4* ep = (const float4*)&ev_s[nn][kh * 16];
      float4 e0 = ep[0], e1 = ep[1], e2 = ep[2], e3 = ep[3];
      acc[0]  = fmaf(e0.x, a, acc[0]);  acc[1]  = fmaf(e0.y, a, acc[1]);
      acc[2]  = fmaf(e0.z, a, acc[2]);  acc[3]  = fmaf(e0.w, a, acc[3]);
      acc[4]  = fmaf(e1.x, a, acc[4]);  acc[5]  = fmaf(e1.y, a, acc[5]);
      acc[6]  = fmaf(e1.z, a, acc[6]);  acc[7]  = fmaf(e1.w, a, acc[7]);
      acc[8]  = fmaf(e2.x, a, acc[8]);  acc[9]  = fmaf(e2.y, a, acc[9]);
      acc[10] = fmaf(e2.z, a, acc[10]); acc[11] = fmaf(e2.w, a, acc[11]);
      acc[12] = fmaf(e3.x, a, acc[12]); acc[13] = fmaf(e3.y, a, acc[13]);
      acc[14] = fmaf(e3.z, a, acc[14]); acc[15] = fmaf(e3.w, a, acc[15]);
    }
    __syncthreads();
  }
  float* sp = spec + ((size_t)b * KD + kt * 32 + kh * 16) * CD + c;
#pragma unroll
  for (int kk = 0; kk < 16; ++kk) unsafeAtomicAdd(sp + kk * CD, acc[kk]);
}

// spec[b,k,c] *= exp(-evals[b,k] * max(|t_diff[blk,c]|, 1e-8))
__global__ void k_scale_spec(float* spec, const float* __restrict__ evals,
                             const float* __restrict__ tdiff, int blk) {
  int i = blockIdx.x * 256 + threadIdx.x;   // over 8*128*128
  int c = i & 127;
  int k = (i >> 7) & 127;
  int b = i >> 14;
  float tm = fmaxf(fabsf(tdiff[blk * CD + c]), 1e-8f);
  spec[i] *= expf(-evals[b * KD + k] * tm);
}

// h_diff[n,c] = sum_k ev[n,k] * spec[b,k,c]   (32 nodes/block, 4x4 micro-tile)
__global__ void k_from_basis(const float* __restrict__ evecs, const float* __restrict__ spec,
                             float* __restrict__ hdiff) {
  const int BPG = 391;                 // ceil(12500/32)
  int b  = blockIdx.x / BPG;
  int nb = (blockIdx.x % BPG) * 32;
  int t = threadIdx.x, cg = t & 31, ng = t >> 5;
  __shared__ float evT[128][36];
  size_t gbase = (size_t)b * NPG;
#pragma unroll
  for (int l = 0; l < 16; ++l) {
    int idx = l * 256 + t;
    int row = idx >> 7, col = idx & 127;
    evT[col][row] = (nb + row < NPG) ? evecs[(gbase + nb + row) * KD + col] : 0.f;
  }
  __syncthreads();
  const float* sp = spec + (size_t)b * KD * CD;
  float acc[4][4] = {};
#pragma unroll 8
  for (int k = 0; k < KD; ++k) {
    float4 e = *(const float4*)&evT[k][ng * 4];
    float4 s = *(const float4*)(sp + k * CD + cg * 4);
    OUTER4(acc, e, s);
  }
#pragma unroll
  for (int i = 0; i < 4; ++i) {
    int n = nb + ng * 4 + i;
    if (n < NPG) {
      float4 o = make_float4(acc[i][0], acc[i][1], acc[i][2], acc[i][3]);
      *(float4*)&hdiff[(gbase + n) * CD + cg * 4] = o;
    }
  }
}

// g_re[r,:] += vre[e]*h_diff[col,:], g_im likewise. 8 edges / 256-thread block.
__global__ void k_scatter(const int* __restrict__ rows, const int* __restrict__ cols,
                          const float* __restrict__ vre, const float* __restrict__ vim,
                          const float* __restrict__ hd, float* g_re, float* g_im) {
  int eg = threadIdx.x >> 5;
  int cg = threadIdx.x & 31;
  int e  = blockIdx.x * 8 + eg;
  int r = rows[e], col = cols[e];
  float a = vre[e], bb = vim[e];
  float4 v = *(const float4*)&hd[(size_t)col * CD + cg * 4];
  float* pre = &g_re[(size_t)r * CD + cg * 4];
  float* pim = &g_im[(size_t)r * CD + cg * 4];
  unsafeAtomicAdd(pre + 0, a * v.x);
  unsafeAtomicAdd(pre + 1, a * v.y);
  unsafeAtomicAdd(pre + 2, a * v.z);
  unsafeAtomicAdd(pre + 3, a * v.w);
  unsafeAtomicAdd(pim + 0, bb * v.x);
  unsafeAtomicAdd(pim + 1, bb * v.y);
  unsafeAtomicAdd(pim + 2, bb * v.z);
  unsafeAtomicAdd(pim + 3, bb * v.w);
}

// g_feat = tanh(g_re * (g_re@A^T) + g_im * (g_im@A^T)); result overwrites g_re
__global__ void k_gfeat(float* g_re, float* g_im, const float* __restrict__ A_T) {
  int nb = blockIdx.x * 32;
  int t = threadIdx.x, cg = t & 31, ng = t >> 5;
  __shared__ float reT[128][36];
  __shared__ float imT[128][36];
#pragma unroll
  for (int l = 0; l < 16; ++l) {
    int idx = l * 256 + t;
    int row = idx >> 7, col = idx & 127;
    size_t base = (size_t)(nb + row) * CD + col;
    reT[col][row] = g_re[base];
    imT[col][row] = g_im[base];
  }
  __syncthreads();
  float ar[4][4] = {}, ai[4][4] = {};
#pragma unroll 4
  for (int j = 0; j < CD; ++j) {
    float4 a  = *(const float4*)&A_T[j * CD + cg * 4];
    float4 er = *(const float4*)&reT[j][ng * 4];
    float4 ei = *(const float4*)&imT[j][ng * 4];
    OUTER4(ar, er, a);
    OUTER4(ai, ei, a);
  }
#pragma unroll
  for (int i = 0; i < 4; ++i) {
    int n = nb + ng * 4 + i;
    float4 o;
    o.x = tanhf(fmaf(reT[cg*4+0][ng*4+i], ar[i][0], imT[cg*4+0][ng*4+i] * ai[i][0]));
    o.y = tanhf(fmaf(reT[cg*4+1][ng*4+i], ar[i][1], imT[cg*4+1][ng*4+i] * ai[i][1]));
    o.z = tanhf(fmaf(reT[cg*4+2][ng*4+i], ar[i][2], imT[cg*4+2][ng*4+i] * ai[i][2]));
    o.w = tanhf(fmaf(reT[cg*4+3][ng*4+i], ar[i][3], imT[cg*4+3][ng*4+i] * ai[i][3]));
    *(float4*)&g_re[(size_t)n * CD + cg * 4] = o;
  }
}

// t1 = relu([h|h_diff|g_feat] @ W1 + b1)  -> stored in g_im buffer
__global__ void k_mlp1(const float* __restrict__ h, const float* __restrict__ hdiff,
                       const float* __restrict__ gfeat, const float* __restrict__ W1,
                       const float* __restrict__ b1, float* __restrict__ t1) {
  int nb = blockIdx.x * 32;
  int t = threadIdx.x, cg = t & 31, ng = t >> 5;
  __shared__ float cT[3 * CD][36];
#pragma unroll
  for (int l = 0; l < 16; ++l) {
    int idx = l * 256 + t;
    int row = idx >> 7, col = idx & 127;
    size_t base = (size_t)(nb + row) * CD + col;
    cT[col][row]          = h[base];
    cT[CD + col][row]     = hdiff[base];
    cT[2 * CD + col][row] = gfeat[base];
  }
  __syncthreads();
  float acc[4][4] = {};
#pragma unroll 8
  for (int k = 0; k < 3 * CD; ++k) {
    float4 e = *(const float4*)&cT[k][ng * 4];
    float4 w = *(const float4*)&W1[k * CD + cg * 4];
    OUTER4(acc, e, w);
  }
#pragma unroll
  for (int i = 0; i < 4; ++i) {
    int n = nb + ng * 4 + i;
    float4 o;
    o.x = fmaxf(acc[i][0] + b1[cg * 4 + 0], 0.f);
    o.y = fmaxf(acc[i][1] + b1[cg * 4 + 1], 0.f);
    o.z = fmaxf(acc[i][2] + b1[cg * 4 + 2], 0.f);
    o.w = fmaxf(acc[i][3] + b1[cg * 4 + 3], 0.f);
    *(float4*)&t1[(size_t)n * CD + cg * 4] = o;
  }
}

// h += t1 @ W2 + b2
__global__ void k_mlp2(const float* __restrict__ t1, const float* __restrict__ W2,
                       const float* __restrict__ b2, float* h) {
  int nb = blockIdx.x * 32;
  int t = threadIdx.x, cg = t & 31, ng = t >> 5;
  __shared__ float aT[CD][36];
#pragma unroll
  for (int l = 0; l < 16; ++l) {
    int idx = l * 256 + t;
    int row = idx >> 7, col = idx & 127;
    aT[col][row] = t1[(size_t)(nb + row) * CD + col];
  }
  __syncthreads();
  float acc[4][4] = {};
#pragma unroll 8
  for (int k = 0; k < CD; ++k) {
    float4 e = *(const float4*)&aT[k][ng * 4];
    float4 w = *(const float4*)&W2[k * CD + cg * 4];
    OUTER4(acc, e, w);
  }
#pragma unroll
  for (int i = 0; i < 4; ++i) {
    size_t n = nb + ng * 4 + i;
    float4* hp = (float4*)&h[n * CD + cg * 4];
    float4 hv = *hp;
    hv.x += acc[i][0] + b2[cg * 4 + 0];
    hv.y += acc[i][1] + b2[cg * 4 + 1];
    hv.z += acc[i][2] + b2[cg * 4 + 2];
    hv.w += acc[i][3] + b2[cg * 4 + 3];
    *hp = hv;
  }
}

// out = relu([h | gs[batch]] @ Wh1 + bh1) @ Wh2 + bh2 ; 4 nodes (waves) / block
__global__ void k_head(const float* __restrict__ h, const float* __restrict__ gs,
                       const int* __restrict__ batch,
                       const float* __restrict__ Wh1, const float* __restrict__ bh1,
                       const float* __restrict__ Wh2, const float* __restrict__ bh2,
                       float* __restrict__ out) {
  int w = threadIdx.x >> 6;
  int j = threadIdx.x & 63;
  int n = blockIdx.x * 4 + w;
  int b = batch[n];
  __shared__ float hs[4][128];
  __shared__ float zs[4][64];
  hs[w][j]      = h[(size_t)n * CD + j];
  hs[w][j + 64] = h[(size_t)n * CD + 64 + j];
  __syncthreads();
  float acc = bh1[j];
#pragma unroll 16
  for (int k = 0; k < CD; ++k) acc = fmaf(hs[w][k], Wh1[k * 64 + j], acc);
#pragma unroll
  for (int i = 0; i < GSDIM; ++i) acc = fmaf(gs[b * GSDIM + i], Wh1[(CD + i) * 64 + j], acc);
  zs[w][j] = fmaxf(acc, 0.f);
  __syncthreads();
  if (j < NCLF) {
    float o = bh2[j];
#pragma unroll 16
    for (int k = 0; k < 64; ++k) o = fmaf(zs[w][k], Wh2[k * NCLF + j], o);
    out[(size_t)n * NCLF + j] = o;
  }
}

extern "C" void kernel_launch(void* const* d_in, const int* in_sizes, int n_in,
                              void* d_out, int out_size, void* d_ws, size_t ws_size,
                              hipStream_t stream) {
  const float* x     = (const float*)d_in[0];
  const float* evals = (const float*)d_in[1];
  const float* evecs = (const float*)d_in[2];
  const float* mass  = (const float*)d_in[3];
  const float* gs    = (const float*)d_in[4];
  const int*   batch = (const int*)d_in[5];
  const int*   grows = (const int*)d_in[6];
  const int*   gcols = (const int*)d_in[7];
  const float* vre   = (const float*)d_in[8];
  const float* vim   = (const float*)d_in[9];
  const float* Wemb  = (const float*)d_in[11];
  const float* bemb  = (const float*)d_in[12];
  const float* tdiff = (const float*)d_in[13];
  const float* Agrad = (const float*)d_in[14];
  const float* W1    = (const float*)d_in[15];
  const float* b1    = (const float*)d_in[16];
  const float* W2    = (const float*)d_in[17];
  const float* b2    = (const float*)d_in[18];
  const float* Wh1   = (const float*)d_in[19];
  const float* bh1   = (const float*)d_in[20];
  const float* Wh2   = (const float*)d_in[21];
  const float* bh2   = (const float*)d_in[22];

  float* ws = (float*)d_ws;
  const size_t NC = (size_t)NNODES * CD;       // 12.8M floats
  float* h     = ws;
  float* hdiff = ws + NC;
  float* g_re  = ws + 2 * NC;
  float* g_im  = ws + 3 * NC;
  float* spec  = ws + 4 * NC;                  // 8*128*128
  float* A_T   = spec + (size_t)NGRAPH * KD * CD;  // 4*128*128
  float* out   = (float*)d_out;

  k_embed<<<NNODES / 2, 256, 0, stream>>>(x, Wemb, bemb, h);
  k_transA<<<(NBLKS * CD * CD) / 256, 256, 0, stream>>>(Agrad, A_T);

  const int fill4 = (int)((2 * NC + (size_t)NGRAPH * KD * CD) / 4);
  for (int blk = 0; blk < NBLKS; ++blk) {
    k_fill0<<<2048, 256, 0, stream>>>((float4*)g_re, fill4);   // zeroes g_re,g_im,spec
    k_to_basis<<<NGRAPH * 4 * TBSPLIT, 256, 0, stream>>>(evecs, h, mass, spec);
    k_scale_spec<<<(NGRAPH * KD * CD) / 256, 256, 0, stream>>>(spec, evals, tdiff, blk);
    k_from_basis<<<NGRAPH * 391, 256, 0, stream>>>(evecs, spec, hdiff);
    k_scatter<<<NEDGE / 8, 256, 0, stream>>>(grows, gcols, vre, vim, hdiff, g_re, g_im);
    k_gfeat<<<NNODES / 32, 256, 0, stream>>>(g_re, g_im, A_T + (size_t)blk * CD * CD);
    k_mlp1<<<NNODES / 32, 256, 0, stream>>>(h, hdiff, g_re,
                                            W1 + (size_t)blk * 3 * CD * CD, b1 + blk * CD, g_im);
    k_mlp2<<<NNODES / 32, 256, 0, stream>>>(g_im, W2 + (size_t)blk * CD * CD, b2 + blk * CD, h);
  }
  k_head<<<NNODES / 4, 256, 0, stream>>>(h, gs, batch, Wh1, bh1, Wh2, bh2, out);
}

// Round 2
// 6669.917 us; speedup vs baseline: 2.1642x; 2.1642x over previous
//
#include <hip/hip_runtime.h>
#include <hip/hip_bf16.h>

#define NNODES 100000
#define NPG    12500
#define NGRAPH 8
#define KD     128
#define CD     128
#define INDIM  7
#define GSDIM  11
#define NBLKS  4
#define NCLF   5
#define NEDGE  800000
#define TBSPLIT 16

// 4x4 outer-product accumulate: ACC[i][q] += E_i * S_q
#define OUTER4(ACC, E, S) do {                                              \
  ACC[0][0] = fmaf((E).x,(S).x,ACC[0][0]); ACC[0][1] = fmaf((E).x,(S).y,ACC[0][1]); \
  ACC[0][2] = fmaf((E).x,(S).z,ACC[0][2]); ACC[0][3] = fmaf((E).x,(S).w,ACC[0][3]); \
  ACC[1][0] = fmaf((E).y,(S).x,ACC[1][0]); ACC[1][1] = fmaf((E).y,(S).y,ACC[1][1]); \
  ACC[1][2] = fmaf((E).y,(S).z,ACC[1][2]); ACC[1][3] = fmaf((E).y,(S).w,ACC[1][3]); \
  ACC[2][0] = fmaf((E).z,(S).x,ACC[2][0]); ACC[2][1] = fmaf((E).z,(S).y,ACC[2][1]); \
  ACC[2][2] = fmaf((E).z,(S).z,ACC[2][2]); ACC[2][3] = fmaf((E).z,(S).w,ACC[2][3]); \
  ACC[3][0] = fmaf((E).w,(S).x,ACC[3][0]); ACC[3][1] = fmaf((E).w,(S).y,ACC[3][1]); \
  ACC[3][2] = fmaf((E).w,(S).z,ACC[3][2]); ACC[3][3] = fmaf((E).w,(S).w,ACC[3][3]); \
} while (0)

__global__ void k_fill0(float4* p, int n4) {
  int i = blockIdx.x * blockDim.x + threadIdx.x;
  int s = gridDim.x * blockDim.x;
  float4 z = make_float4(0.f, 0.f, 0.f, 0.f);
  for (; i < n4; i += s) p[i] = z;
}

// h = relu(x @ W_embed + b_embed); 2 nodes per 256-thread block
__global__ void k_embed(const float* __restrict__ x, const float* __restrict__ W,
                        const float* __restrict__ bv, float* __restrict__ h) {
  int w = threadIdx.x >> 7;
  int c = threadIdx.x & 127;
  int n = blockIdx.x * 2 + w;
  __shared__ float xs[2][INDIM];
  if (c < INDIM) xs[w][c] = x[n * INDIM + c];
  __syncthreads();
  float acc = bv[c];
#pragma unroll
  for (int i = 0; i < INDIM; ++i) acc = fmaf(xs[w][i], W[i * CD + c], acc);
  h[(size_t)n * CD + c] = fmaxf(acc, 0.f);
}

// A_T[blk][j][c] = A[blk][c][j]
__global__ void k_transA(const float* __restrict__ A, float* __restrict__ A_T) {
  int i = blockIdx.x * 256 + threadIdx.x;     // over 4*128*128
  int c = i & 127, j = (i >> 7) & 127, blk = i >> 14;
  A_T[i] = A[blk * 16384 + c * 128 + j];
}

// ---- ONCE per launch: GreEV[r,:] += vre[e]*evecs[col,:], GimEV likewise ----
// 8 edges / 256-thread block, fp32 atomic accumulation.
__global__ void k_scatter_ev(const int* __restrict__ rows, const int* __restrict__ cols,
                             const float* __restrict__ vre, const float* __restrict__ vim,
                             const float* __restrict__ ev, float* gre, float* gim) {
  int eg = threadIdx.x >> 5;
  int cg = threadIdx.x & 31;
  int e  = blockIdx.x * 8 + eg;
  int r = rows[e], col = cols[e];
  float a = vre[e], bb = vim[e];
  float4 v = *(const float4*)&ev[(size_t)col * KD + cg * 4];
  float* pre = &gre[(size_t)r * KD + cg * 4];
  float* pim = &gim[(size_t)r * KD + cg * 4];
  unsafeAtomicAdd(pre + 0, a * v.x);
  unsafeAtomicAdd(pre + 1, a * v.y);
  unsafeAtomicAdd(pre + 2, a * v.z);
  unsafeAtomicAdd(pre + 3, a * v.w);
  unsafeAtomicAdd(pim + 0, bb * v.x);
  unsafeAtomicAdd(pim + 1, bb * v.y);
  unsafeAtomicAdd(pim + 2, bb * v.z);
  unsafeAtomicAdd(pim + 3, bb * v.w);
}

// fp32 -> bf16 (bit-packed ushort) conversion
__global__ void k_cvt_bf16(const float4* __restrict__ in, ushort4* __restrict__ out, int n4) {
  int i = blockIdx.x * blockDim.x + threadIdx.x;
  int s = gridDim.x * blockDim.x;
  for (; i < n4; i += s) {
    float4 v = in[i];
    __hip_bfloat16 a = __float2bfloat16(v.x), b = __float2bfloat16(v.y);
    __hip_bfloat16 c = __float2bfloat16(v.z), d = __float2bfloat16(v.w);
    ushort4 o;
    o.x = *(unsigned short*)&a; o.y = *(unsigned short*)&b;
    o.z = *(unsigned short*)&c; o.w = *(unsigned short*)&d;
    out[i] = o;
  }
}

// spec[b,k,c] += sum_n ev[b,n,k] * h[b,n,c] * mass[b,n]   (split-n + atomics)
__global__ void k_to_basis(const float* __restrict__ evecs, const float* __restrict__ h,
                           const float* __restrict__ mass, float* spec) {
  int wg = blockIdx.x;
  int b  = wg >> 6;           // 4 ktiles * 16 splits = 64 per graph
  int kt = (wg >> 4) & 3;
  int ns = wg & 15;
  int t  = threadIdx.x;
  int c  = t & 127;
  int kh = t >> 7;            // 0..1, k-halves of 16
  const int nchunk = (NPG + TBSPLIT - 1) / TBSPLIT;   // 782
  int n0 = ns * nchunk;
  int n1 = min(n0 + nchunk, NPG);
  __shared__ float hm_s[32][128];
  __shared__ float ev_s[32][32];
  float acc[16];
#pragma unroll
  for (int i = 0; i < 16; ++i) acc[i] = 0.f;
  size_t gbase = (size_t)b * NPG;
  for (int nb = n0; nb < n1; nb += 32) {
#pragma unroll
    for (int l = 0; l < 16; ++l) {
      int idx = l * 256 + t;
      int row = idx >> 7, col = idx & 127;
      int n = nb + row;
      float v = 0.f;
      if (n < n1) v = h[(gbase + n) * CD + col] * mass[gbase + n];
      hm_s[row][col] = v;
    }
#pragma unroll
    for (int l = 0; l < 4; ++l) {
      int idx = l * 256 + t;
      int row = idx >> 5, kk = idx & 31;
      int n = nb + row;
      ev_s[row][kk] = (n < n1) ? evecs[(gbase + n) * KD + kt * 32 + kk] : 0.f;
    }
    __syncthreads();
#pragma unroll
    for (int nn = 0; nn < 32; ++nn) {
      float a = hm_s[nn][c];
      const float4* ep = (const float4*)&ev_s[nn][kh * 16];
      float4 e0 = ep[0], e1 = ep[1], e2 = ep[2], e3 = ep[3];
      acc[0]  = fmaf(e0.x, a, acc[0]);  acc[1]  = fmaf(e0.y, a, acc[1]);
      acc[2]  = fmaf(e0.z, a, acc[2]);  acc[3]  = fmaf(e0.w, a, acc[3]);
      acc[4]  = fmaf(e1.x, a, acc[4]);  acc[5]  = fmaf(e1.y, a, acc[5]);
      acc[6]  = fmaf(e1.z, a, acc[6]);  acc[7]  = fmaf(e1.w, a, acc[7]);
      acc[8]  = fmaf(e2.x, a, acc[8]);  acc[9]  = fmaf(e2.y, a, acc[9]);
      acc[10] = fmaf(e2.z, a, acc[10]); acc[11] = fmaf(e2.w, a, acc[11]);
      acc[12] = fmaf(e3.x, a, acc[12]); acc[13] = fmaf(e3.y, a, acc[13]);
      acc[14] = fmaf(e3.z, a, acc[14]); acc[15] = fmaf(e3.w, a, acc[15]);
    }
    __syncthreads();
  }
  float* sp = spec + ((size_t)b * KD + kt * 32 + kh * 16) * CD + c;
#pragma unroll
  for (int kk = 0; kk < 16; ++kk) unsafeAtomicAdd(sp + kk * CD, acc[kk]);
}

// spec[b,k,c] *= exp(-evals[b,k] * max(|t_diff[blk,c]|, 1e-8))
__global__ void k_scale_spec(float* spec, const float* __restrict__ evals,
                             const float* __restrict__ tdiff, int blk) {
  int i = blockIdx.x * 256 + threadIdx.x;   // over 8*128*128
  int c = i & 127;
  int k = (i >> 7) & 127;
  int b = i >> 14;
  float tm = fmaxf(fabsf(tdiff[blk * CD + c]), 1e-8f);
  spec[i] *= expf(-evals[b * KD + k] * tm);
}

// SA[b,k,j] = sum_c spec[b,k,c] * A[j,c]  (A_T layout: A_T[c*CD+j] = A[j,c])
// grid: 8 graphs x 4 ktiles of 32 rows
__global__ void k_specA(const float* __restrict__ spec, const float* __restrict__ A_T,
                        float* __restrict__ SA) {
  int b  = blockIdx.x >> 2;
  int kt = (blockIdx.x & 3) * 32;
  int t = threadIdx.x, cg = t & 31, ng = t >> 5;
  __shared__ float sT[128][36];
  const float* sp = spec + ((size_t)b * KD + kt) * CD;
#pragma unroll
  for (int l = 0; l < 16; ++l) {
    int idx = l * 256 + t;
    int row = idx >> 7, col = idx & 127;
    sT[col][row] = sp[row * CD + col];
  }
  __syncthreads();
  float acc[4][4] = {};
#pragma unroll 8
  for (int c = 0; c < CD; ++c) {
    float4 e = *(const float4*)&sT[c][ng * 4];
    float4 w = *(const float4*)(A_T + c * CD + cg * 4);
    OUTER4(acc, e, w);
  }
  float* op = SA + ((size_t)b * KD + kt) * CD;
#pragma unroll
  for (int i = 0; i < 4; ++i)
    *(float4*)(op + (ng * 4 + i) * CD + cg * 4) =
        make_float4(acc[i][0], acc[i][1], acc[i][2], acc[i][3]);
}

// h_diff[n,c] = sum_k ev[n,k] * spec[b,k,c]   (32 nodes/block, 4x4 micro-tile)
__global__ void k_from_basis(const float* __restrict__ evecs, const float* __restrict__ spec,
                             float* __restrict__ hdiff) {
  const int BPG = 391;                 // ceil(12500/32)
  int b  = blockIdx.x / BPG;
  int nb = (blockIdx.x % BPG) * 32;
  int t = threadIdx.x, cg = t & 31, ng = t >> 5;
  __shared__ float evT[128][36];
  size_t gbase = (size_t)b * NPG;
#pragma unroll
  for (int l = 0; l < 16; ++l) {
    int idx = l * 256 + t;
    int row = idx >> 7, col = idx & 127;
    evT[col][row] = (nb + row < NPG) ? evecs[(gbase + nb + row) * KD + col] : 0.f;
  }
  __syncthreads();
  const float* sp = spec + (size_t)b * KD * CD;
  float acc[4][4] = {};
#pragma unroll 8
  for (int k = 0; k < KD; ++k) {
    float4 e = *(const float4*)&evT[k][ng * 4];
    float4 s = *(const float4*)(sp + k * CD + cg * 4);
    OUTER4(acc, e, s);
  }
#pragma unroll
  for (int i = 0; i < 4; ++i) {
    int n = nb + ng * 4 + i;
    if (n < NPG) {
      float4 o = make_float4(acc[i][0], acc[i][1], acc[i][2], acc[i][3]);
      *(float4*)&hdiff[(gbase + n) * CD + cg * 4] = o;
    }
  }
}

// g_feat = tanh((GreEV@spec')*(GreEV@SA) + (GimEV@spec')*(GimEV@SA))
// GreEV/GimEV bf16 [N,K]; spec'/SA fp32 [B,K,C]. 32 nodes/block.
__global__ void k_gfeat2(const unsigned short* __restrict__ gre16,
                         const unsigned short* __restrict__ gim16,
                         const float* __restrict__ spec, const float* __restrict__ SA,
                         float* __restrict__ gfeat) {
  const int BPG = 391;
  int b  = blockIdx.x / BPG;
  int nb = (blockIdx.x % BPG) * 32;
  int t = threadIdx.x, cg = t & 31, ng = t >> 5;
  __shared__ float reT[128][36];
  __shared__ float imT[128][36];
  size_t gbase = (size_t)b * NPG;
  {
    int node = t & 31, kg = t >> 5;            // 32 nodes x 8 kgroups x 16 k
    uint4 r0 = {0,0,0,0}, r1 = {0,0,0,0}, i0 = {0,0,0,0}, i1 = {0,0,0,0};
    if (nb + node < NPG) {
      size_t base = (gbase + nb + node) * (size_t)KD + kg * 16;
      r0 = *(const uint4*)(gre16 + base);
      r1 = *(const uint4*)(gre16 + base + 8);
      i0 = *(const uint4*)(gim16 + base);
      i1 = *(const uint4*)(gim16 + base + 8);
    }
    unsigned short rr[16], ii[16];
    *(uint4*)&rr[0] = r0; *(uint4*)&rr[8] = r1;
    *(uint4*)&ii[0] = i0; *(uint4*)&ii[8] = i1;
#pragma unroll
    for (int i = 0; i < 16; ++i) {
      reT[kg * 16 + i][node] = __uint_as_float((unsigned)rr[i] << 16);
      imT[kg * 16 + i][node] = __uint_as_float((unsigned)ii[i] << 16);
    }
  }
  __syncthreads();
  const float* sp = spec + (size_t)b * KD * CD;
  const float* sa = SA   + (size_t)b * KD * CD;
  float gr[4][4] = {}, ar[4][4] = {}, gi[4][4] = {}, ai[4][4] = {};
#pragma unroll 4
  for (int k = 0; k < KD; ++k) {
    float4 er = *(const float4*)&reT[k][ng * 4];
    float4 ei = *(const float4*)&imT[k][ng * 4];
    float4 s  = *(const float4*)(sp + k * CD + cg * 4);
    float4 a  = *(const float4*)(sa + k * CD + cg * 4);
    OUTER4(gr, er, s);
    OUTER4(ar, er, a);
    OUTER4(gi, ei, s);
    OUTER4(ai, ei, a);
  }
#pragma unroll
  for (int i = 0; i < 4; ++i) {
    int n = nb + ng * 4 + i;
    if (n < NPG) {
      float4 o;
      o.x = tanhf(fmaf(gr[i][0], ar[i][0], gi[i][0] * ai[i][0]));
      o.y = tanhf(fmaf(gr[i][1], ar[i][1], gi[i][1] * ai[i][1]));
      o.z = tanhf(fmaf(gr[i][2], ar[i][2], gi[i][2] * ai[i][2]));
      o.w = tanhf(fmaf(gr[i][3], ar[i][3], gi[i][3] * ai[i][3]));
      *(float4*)&gfeat[(gbase + n) * CD + cg * 4] = o;
    }
  }
}

// t1 = relu([h|h_diff|g_feat] @ W1 + b1); t1 may alias gfeat (tile-local RW)
__global__ void k_mlp1(const float* __restrict__ h, const float* __restrict__ hdiff,
                       const float* gfeat, const float* __restrict__ W1,
                       const float* __restrict__ b1, float* t1) {
  int nb = blockIdx.x * 32;
  int t = threadIdx.x, cg = t & 31, ng = t >> 5;
  __shared__ float cT[3 * CD][36];
#pragma unroll
  for (int l = 0; l < 16; ++l) {
    int idx = l * 256 + t;
    int row = idx >> 7, col = idx & 127;
    size_t base = (size_t)(nb + row) * CD + col;
    cT[col][row]          = h[base];
    cT[CD + col][row]     = hdiff[base];
    cT[2 * CD + col][row] = gfeat[base];
  }
  __syncthreads();
  float acc[4][4] = {};
#pragma unroll 8
  for (int k = 0; k < 3 * CD; ++k) {
    float4 e = *(const float4*)&cT[k][ng * 4];
    float4 w = *(const float4*)&W1[k * CD + cg * 4];
    OUTER4(acc, e, w);
  }
#pragma unroll
  for (int i = 0; i < 4; ++i) {
    int n = nb + ng * 4 + i;
    float4 o;
    o.x = fmaxf(acc[i][0] + b1[cg * 4 + 0], 0.f);
    o.y = fmaxf(acc[i][1] + b1[cg * 4 + 1], 0.f);
    o.z = fmaxf(acc[i][2] + b1[cg * 4 + 2], 0.f);
    o.w = fmaxf(acc[i][3] + b1[cg * 4 + 3], 0.f);
    *(float4*)&t1[(size_t)n * CD + cg * 4] = o;
  }
}

// h += t1 @ W2 + b2
__global__ void k_mlp2(const float* __restrict__ t1, const float* __restrict__ W2,
                       const float* __restrict__ b2, float* h) {
  int nb = blockIdx.x * 32;
  int t = threadIdx.x, cg = t & 31, ng = t >> 5;
  __shared__ float aT[CD][36];
#pragma unroll
  for (int l = 0; l < 16; ++l) {
    int idx = l * 256 + t;
    int row = idx >> 7, col = idx & 127;
    aT[col][row] = t1[(size_t)(nb + row) * CD + col];
  }
  __syncthreads();
  float acc[4][4] = {};
#pragma unroll 8
  for (int k = 0; k < CD; ++k) {
    float4 e = *(const float4*)&aT[k][ng * 4];
    float4 w = *(const float4*)&W2[k * CD + cg * 4];
    OUTER4(acc, e, w);
  }
#pragma unroll
  for (int i = 0; i < 4; ++i) {
    size_t n = nb + ng * 4 + i;
    float4* hp = (float4*)&h[n * CD + cg * 4];
    float4 hv = *hp;
    hv.x += acc[i][0] + b2[cg * 4 + 0];
    hv.y += acc[i][1] + b2[cg * 4 + 1];
    hv.z += acc[i][2] + b2[cg * 4 + 2];
    hv.w += acc[i][3] + b2[cg * 4 + 3];
    *hp = hv;
  }
}

// out = relu([h | gs[batch]] @ Wh1 + bh1) @ Wh2 + bh2 ; 4 nodes (waves) / block
__global__ void k_head(const float* __restrict__ h, const float* __restrict__ gs,
                       const int* __restrict__ batch,
                       const float* __restrict__ Wh1, const float* __restrict__ bh1,
                       const float* __restrict__ Wh2, const float* __restrict__ bh2,
                       float* __restrict__ out) {
  int w = threadIdx.x >> 6;
  int j = threadIdx.x & 63;
  int n = blockIdx.x * 4 + w;
  int b = batch[n];
  __shared__ float hs[4][128];
  __shared__ float zs[4][64];
  hs[w][j]      = h[(size_t)n * CD + j];
  hs[w][j + 64] = h[(size_t)n * CD + 64 + j];
  __syncthreads();
  float acc = bh1[j];
#pragma unroll 16
  for (int k = 0; k < CD; ++k) acc = fmaf(hs[w][k], Wh1[k * 64 + j], acc);
#pragma unroll
  for (int i = 0; i < GSDIM; ++i) acc = fmaf(gs[b * GSDIM + i], Wh1[(CD + i) * 64 + j], acc);
  zs[w][j] = fmaxf(acc, 0.f);
  __syncthreads();
  if (j < NCLF) {
    float o = bh2[j];
#pragma unroll 16
    for (int k = 0; k < 64; ++k) o = fmaf(zs[w][k], Wh2[k * NCLF + j], o);
    out[(size_t)n * NCLF + j] = o;
  }
}

extern "C" void kernel_launch(void* const* d_in, const int* in_sizes, int n_in,
                              void* d_out, int out_size, void* d_ws, size_t ws_size,
                              hipStream_t stream) {
  const float* x     = (const float*)d_in[0];
  const float* evals = (const float*)d_in[1];
  const float* evecs = (const float*)d_in[2];
  const float* mass  = (const float*)d_in[3];
  const float* gs    = (const float*)d_in[4];
  const int*   batch = (const int*)d_in[5];
  const int*   grows = (const int*)d_in[6];
  const int*   gcols = (const int*)d_in[7];
  const float* vre   = (const float*)d_in[8];
  const float* vim   = (const float*)d_in[9];
  const float* Wemb  = (const float*)d_in[11];
  const float* bemb  = (const float*)d_in[12];
  const float* tdiff = (const float*)d_in[13];
  const float* Agrad = (const float*)d_in[14];
  const float* W1    = (const float*)d_in[15];
  const float* b1    = (const float*)d_in[16];
  const float* W2    = (const float*)d_in[17];
  const float* b2    = (const float*)d_in[18];
  const float* Wh1   = (const float*)d_in[19];
  const float* bh1   = (const float*)d_in[20];
  const float* Wh2   = (const float*)d_in[21];
  const float* bh2   = (const float*)d_in[22];

  float* ws = (float*)d_ws;
  const size_t NC = (size_t)NNODES * CD;       // 12.8M floats
  const size_t NK = (size_t)NNODES * KD;       // 12.8M elems
  float* h     = ws;                           // [N,C]
  float* hdiff = ws + NC;                      // [N,C]  (also fp32 scatter temp re)
  float* gfeat = ws + 2 * NC;                  // [N,C]  (also fp32 scatter temp im; aliases t1)
  unsigned short* Gre16 = (unsigned short*)(ws + 3 * NC);     // [N,K] bf16
  unsigned short* Gim16 = Gre16 + NK;                         // [N,K] bf16
  float* spec  = ws + 4 * NC;                  // [8,128,128]
  float* SA    = spec + (size_t)NGRAPH * KD * CD;
  float* A_T   = SA + (size_t)NGRAPH * KD * CD;   // [4,128,128]
  float* out   = (float*)d_out;

  float* Gre_f32 = hdiff;   // scatter temps (freed before block loop uses hdiff/gfeat)
  float* Gim_f32 = gfeat;

  k_embed<<<NNODES / 2, 256, 0, stream>>>(x, Wemb, bemb, h);
  k_transA<<<(NBLKS * CD * CD) / 256, 256, 0, stream>>>(Agrad, A_T);

  // once: GreEV/GimEV scatter (fp32 atomics) -> bf16 compress
  k_fill0<<<2048, 256, 0, stream>>>((float4*)Gre_f32, (int)(2 * NC / 4));
  k_scatter_ev<<<NEDGE / 8, 256, 0, stream>>>(grows, gcols, vre, vim, evecs, Gre_f32, Gim_f32);
  k_cvt_bf16<<<1024, 256, 0, stream>>>((const float4*)Gre_f32, (ushort4*)Gre16, (int)(2 * NK / 4));

  for (int blk = 0; blk < NBLKS; ++blk) {
    k_fill0<<<128, 256, 0, stream>>>((float4*)spec, (int)(NGRAPH * KD * CD / 4));
    k_to_basis<<<NGRAPH * 4 * TBSPLIT, 256, 0, stream>>>(evecs, h, mass, spec);
    k_scale_spec<<<(NGRAPH * KD * CD) / 256, 256, 0, stream>>>(spec, evals, tdiff, blk);
    k_specA<<<NGRAPH * 4, 256, 0, stream>>>(spec, A_T + (size_t)blk * CD * CD, SA);
    k_from_basis<<<NGRAPH * 391, 256, 0, stream>>>(evecs, spec, hdiff);
    k_gfeat2<<<NGRAPH * 391, 256, 0, stream>>>(Gre16, Gim16, spec, SA, gfeat);
    k_mlp1<<<NNODES / 32, 256, 0, stream>>>(h, hdiff, gfeat,
                                            W1 + (size_t)blk * 3 * CD * CD, b1 + blk * CD, gfeat);
    k_mlp2<<<NNODES / 32, 256, 0, stream>>>(gfeat, W2 + (size_t)blk * CD * CD, b2 + blk * CD, h);
  }
  k_head<<<NNODES / 4, 256, 0, stream>>>(h, gs, batch, Wh1, bh1, Wh2, bh2, out);
}

// Round 3
// 3850.668 us; speedup vs baseline: 3.7488x; 1.7321x over previous
//
#include <hip/hip_runtime.h>
#include <hip/hip_bf16.h>

#define NNODES 100000
#define NPG    12500
#define NGRAPH 8
#define KD     128
#define CD     128
#define INDIM  7
#define GSDIM  11
#define NBLKS  4
#define NCLF   5
#define NEDGE  800000
#define TBSPLIT 16
#define BCAP   64

// 4x4 outer-product accumulate: ACC[i][q] += E_i * S_q
#define OUTER4(ACC, E, S) do {                                              \
  ACC[0][0] = fmaf((E).x,(S).x,ACC[0][0]); ACC[0][1] = fmaf((E).x,(S).y,ACC[0][1]); \
  ACC[0][2] = fmaf((E).x,(S).z,ACC[0][2]); ACC[0][3] = fmaf((E).x,(S).w,ACC[0][3]); \
  ACC[1][0] = fmaf((E).y,(S).x,ACC[1][0]); ACC[1][1] = fmaf((E).y,(S).y,ACC[1][1]); \
  ACC[1][2] = fmaf((E).y,(S).z,ACC[1][2]); ACC[1][3] = fmaf((E).y,(S).w,ACC[1][3]); \
  ACC[2][0] = fmaf((E).z,(S).x,ACC[2][0]); ACC[2][1] = fmaf((E).z,(S).y,ACC[2][1]); \
  ACC[2][2] = fmaf((E).z,(S).z,ACC[2][2]); ACC[2][3] = fmaf((E).z,(S).w,ACC[2][3]); \
  ACC[3][0] = fmaf((E).w,(S).x,ACC[3][0]); ACC[3][1] = fmaf((E).w,(S).y,ACC[3][1]); \
  ACC[3][2] = fmaf((E).w,(S).z,ACC[3][2]); ACC[3][3] = fmaf((E).w,(S).w,ACC[3][3]); \
} while (0)

__global__ void k_fill0(float4* p, int n4) {
  int i = blockIdx.x * blockDim.x + threadIdx.x;
  int s = gridDim.x * blockDim.x;
  float4 z = make_float4(0.f, 0.f, 0.f, 0.f);
  for (; i < n4; i += s) p[i] = z;
}

// h = relu(x @ W_embed + b_embed); 2 nodes per 256-thread block
__global__ void k_embed(const float* __restrict__ x, const float* __restrict__ W,
                        const float* __restrict__ bv, float* __restrict__ h) {
  int w = threadIdx.x >> 7;
  int c = threadIdx.x & 127;
  int n = blockIdx.x * 2 + w;
  __shared__ float xs[2][INDIM];
  if (c < INDIM) xs[w][c] = x[n * INDIM + c];
  __syncthreads();
  float acc = bv[c];
#pragma unroll
  for (int i = 0; i < INDIM; ++i) acc = fmaf(xs[w][i], W[i * CD + c], acc);
  h[(size_t)n * CD + c] = fmaxf(acc, 0.f);
}

// A_T[blk][j][c] = A[blk][c][j]
__global__ void k_transA(const float* __restrict__ A, float* __restrict__ A_T) {
  int i = blockIdx.x * 256 + threadIdx.x;     // over 4*128*128
  int c = i & 127, j = (i >> 7) & 127, blk = i >> 14;
  A_T[i] = A[blk * 16384 + c * 128 + j];
}

// ---- edge bucketing: bucket[r*BCAP + pos] = e ----
__global__ void k_bucket_place(const int* __restrict__ rows, int* cnt, int* bucket) {
  int e = blockIdx.x * 256 + threadIdx.x;
  if (e >= NEDGE) return;
  int r = rows[e];
  int pos = atomicAdd(&cnt[r], 1);
  if (pos < BCAP) bucket[(size_t)r * BCAP + pos] = e;
}

// ---- gather: GreEV[r,:] = sum_{e in row r} vre[e]*evecs[cols[e],:] ; bf16 out ----
// one 64-lane wave per row, 2 cols/lane; 4 rows per 256-thread block
__global__ void k_gather_ev(const int* __restrict__ cnt, const int* __restrict__ bucket,
                            const int* __restrict__ cols,
                            const float* __restrict__ vre, const float* __restrict__ vim,
                            const float* __restrict__ ev,
                            unsigned short* __restrict__ gre, unsigned short* __restrict__ gim) {
  int wv = threadIdx.x >> 6;
  int ln = threadIdx.x & 63;
  int r  = blockIdx.x * 4 + wv;
  if (r >= NNODES) return;
  int d = min(cnt[r], BCAP);
  const int* bk = bucket + (size_t)r * BCAP;
  float2 ra = make_float2(0.f, 0.f), ia = make_float2(0.f, 0.f);
  for (int i = 0; i < d; ++i) {
    int e = bk[i];
    float a = vre[e], b = vim[e];
    float2 v = *(const float2*)&ev[(size_t)cols[e] * KD + ln * 2];
    ra.x = fmaf(a, v.x, ra.x); ra.y = fmaf(a, v.y, ra.y);
    ia.x = fmaf(b, v.x, ia.x); ia.y = fmaf(b, v.y, ia.y);
  }
  __hip_bfloat16 r0 = __float2bfloat16(ra.x), r1 = __float2bfloat16(ra.y);
  __hip_bfloat16 i0 = __float2bfloat16(ia.x), i1 = __float2bfloat16(ia.y);
  ushort2 ro, io;
  ro.x = *(unsigned short*)&r0; ro.y = *(unsigned short*)&r1;
  io.x = *(unsigned short*)&i0; io.y = *(unsigned short*)&i1;
  *(ushort2*)&gre[(size_t)r * KD + ln * 2] = ro;
  *(ushort2*)&gim[(size_t)r * KD + ln * 2] = io;
}

// spec[b,k,c] += sum_n ev[b,n,k] * h[b,n,c] * mass[b,n]   (split-n + atomics)
__global__ void k_to_basis(const float* __restrict__ evecs, const float* __restrict__ h,
                           const float* __restrict__ mass, float* spec) {
  int wg = blockIdx.x;
  int b  = wg >> 6;           // 4 ktiles * 16 splits = 64 per graph
  int kt = (wg >> 4) & 3;
  int ns = wg & 15;
  int t  = threadIdx.x;
  int c  = t & 127;
  int kh = t >> 7;            // 0..1, k-halves of 16
  const int nchunk = (NPG + TBSPLIT - 1) / TBSPLIT;   // 782
  int n0 = ns * nchunk;
  int n1 = min(n0 + nchunk, NPG);
  __shared__ float hm_s[32][128];
  __shared__ float ev_s[32][32];
  float acc[16];
#pragma unroll
  for (int i = 0; i < 16; ++i) acc[i] = 0.f;
  size_t gbase = (size_t)b * NPG;
  for (int nb = n0; nb < n1; nb += 32) {
#pragma unroll
    for (int l = 0; l < 16; ++l) {
      int idx = l * 256 + t;
      int row = idx >> 7, col = idx & 127;
      int n = nb + row;
      float v = 0.f;
      if (n < n1) v = h[(gbase + n) * CD + col] * mass[gbase + n];
      hm_s[row][col] = v;
    }
#pragma unroll
    for (int l = 0; l < 4; ++l) {
      int idx = l * 256 + t;
      int row = idx >> 5, kk = idx & 31;
      int n = nb + row;
      ev_s[row][kk] = (n < n1) ? evecs[(gbase + n) * KD + kt * 32 + kk] : 0.f;
    }
    __syncthreads();
#pragma unroll
    for (int nn = 0; nn < 32; ++nn) {
      float a = hm_s[nn][c];
      const float4* ep = (const float4*)&ev_s[nn][kh * 16];
      float4 e0 = ep[0], e1 = ep[1], e2 = ep[2], e3 = ep[3];
      acc[0]  = fmaf(e0.x, a, acc[0]);  acc[1]  = fmaf(e0.y, a, acc[1]);
      acc[2]  = fmaf(e0.z, a, acc[2]);  acc[3]  = fmaf(e0.w, a, acc[3]);
      acc[4]  = fmaf(e1.x, a, acc[4]);  acc[5]  = fmaf(e1.y, a, acc[5]);
      acc[6]  = fmaf(e1.z, a, acc[6]);  acc[7]  = fmaf(e1.w, a, acc[7]);
      acc[8]  = fmaf(e2.x, a, acc[8]);  acc[9]  = fmaf(e2.y, a, acc[9]);
      acc[10] = fmaf(e2.z, a, acc[10]); acc[11] = fmaf(e2.w, a, acc[11]);
      acc[12] = fmaf(e3.x, a, acc[12]); acc[13] = fmaf(e3.y, a, acc[13]);
      acc[14] = fmaf(e3.z, a, acc[14]); acc[15] = fmaf(e3.w, a, acc[15]);
    }
    __syncthreads();
  }
  float* sp = spec + ((size_t)b * KD + kt * 32 + kh * 16) * CD + c;
#pragma unroll
  for (int kk = 0; kk < 16; ++kk) unsafeAtomicAdd(sp + kk * CD, acc[kk]);
}

// spec[b,k,c] *= exp(-evals[b,k] * max(|t_diff[blk,c]|, 1e-8))
__global__ void k_scale_spec(float* spec, const float* __restrict__ evals,
                             const float* __restrict__ tdiff, int blk) {
  int i = blockIdx.x * 256 + threadIdx.x;   // over 8*128*128
  int c = i & 127;
  int k = (i >> 7) & 127;
  int b = i >> 14;
  float tm = fmaxf(fabsf(tdiff[blk * CD + c]), 1e-8f);
  spec[i] *= expf(-evals[b * KD + k] * tm);
}

// SA[b,k,j] = sum_c spec[b,k,c] * A[j,c]  (A_T layout: A_T[c*CD+j] = A[j,c])
__global__ void k_specA(const float* __restrict__ spec, const float* __restrict__ A_T,
                        float* __restrict__ SA) {
  int b  = blockIdx.x >> 2;
  int kt = (blockIdx.x & 3) * 32;
  int t = threadIdx.x, cg = t & 31, ng = t >> 5;
  __shared__ float sT[128][36];
  const float* sp = spec + ((size_t)b * KD + kt) * CD;
#pragma unroll
  for (int l = 0; l < 16; ++l) {
    int idx = l * 256 + t;
    int row = idx >> 7, col = idx & 127;
    sT[col][row] = sp[row * CD + col];
  }
  __syncthreads();
  float acc[4][4] = {};
#pragma unroll 8
  for (int c = 0; c < CD; ++c) {
    float4 e = *(const float4*)&sT[c][ng * 4];
    float4 w = *(const float4*)(A_T + c * CD + cg * 4);
    OUTER4(acc, e, w);
  }
  float* op = SA + ((size_t)b * KD + kt) * CD;
#pragma unroll
  for (int i = 0; i < 4; ++i)
    *(float4*)(op + (ng * 4 + i) * CD + cg * 4) =
        make_float4(acc[i][0], acc[i][1], acc[i][2], acc[i][3]);
}

// M1[b,k,c] = sum_j spec[b,k,j] * W1b[j*CD + c]   (W1b = rows 128..255 of W1[blk])
__global__ void k_specW1(const float* __restrict__ spec, const float* __restrict__ W1b,
                         float* __restrict__ M1) {
  int b  = blockIdx.x >> 2;
  int kt = (blockIdx.x & 3) * 32;
  int t = threadIdx.x, cg = t & 31, ng = t >> 5;
  __shared__ float sT[128][36];
  const float* sp = spec + ((size_t)b * KD + kt) * CD;
#pragma unroll
  for (int l = 0; l < 16; ++l) {
    int idx = l * 256 + t;
    int row = idx >> 7, col = idx & 127;
    sT[col][row] = sp[row * CD + col];
  }
  __syncthreads();
  float acc[4][4] = {};
#pragma unroll 8
  for (int j = 0; j < CD; ++j) {
    float4 e = *(const float4*)&sT[j][ng * 4];
    float4 w = *(const float4*)(W1b + j * CD + cg * 4);
    OUTER4(acc, e, w);
  }
  float* op = M1 + ((size_t)b * KD + kt) * CD;
#pragma unroll
  for (int i = 0; i < 4; ++i)
    *(float4*)(op + (ng * 4 + i) * CD + cg * 4) =
        make_float4(acc[i][0], acc[i][1], acc[i][2], acc[i][3]);
}

// g_feat = tanh((GreEV@spec')*(GreEV@SA) + (GimEV@spec')*(GimEV@SA))
__global__ void k_gfeat2(const unsigned short* __restrict__ gre16,
                         const unsigned short* __restrict__ gim16,
                         const float* __restrict__ spec, const float* __restrict__ SA,
                         float* __restrict__ gfeat) {
  const int BPG = 391;
  int b  = blockIdx.x / BPG;
  int nb = (blockIdx.x % BPG) * 32;
  int t = threadIdx.x, cg = t & 31, ng = t >> 5;
  __shared__ float reT[128][36];
  __shared__ float imT[128][36];
  size_t gbase = (size_t)b * NPG;
  {
    int node = t & 31, kg = t >> 5;            // 32 nodes x 8 kgroups x 16 k
    uint4 r0 = {0,0,0,0}, r1 = {0,0,0,0}, i0 = {0,0,0,0}, i1 = {0,0,0,0};
    if (nb + node < NPG) {
      size_t base = (gbase + nb + node) * (size_t)KD + kg * 16;
      r0 = *(const uint4*)(gre16 + base);
      r1 = *(const uint4*)(gre16 + base + 8);
      i0 = *(const uint4*)(gim16 + base);
      i1 = *(const uint4*)(gim16 + base + 8);
    }
    unsigned short rr[16], ii[16];
    *(uint4*)&rr[0] = r0; *(uint4*)&rr[8] = r1;
    *(uint4*)&ii[0] = i0; *(uint4*)&ii[8] = i1;
#pragma unroll
    for (int i = 0; i < 16; ++i) {
      reT[kg * 16 + i][node] = __uint_as_float((unsigned)rr[i] << 16);
      imT[kg * 16 + i][node] = __uint_as_float((unsigned)ii[i] << 16);
    }
  }
  __syncthreads();
  const float* sp = spec + (size_t)b * KD * CD;
  const float* sa = SA   + (size_t)b * KD * CD;
  float gr[4][4] = {}, ar[4][4] = {}, gi[4][4] = {}, ai[4][4] = {};
#pragma unroll 4
  for (int k = 0; k < KD; ++k) {
    float4 er = *(const float4*)&reT[k][ng * 4];
    float4 ei = *(const float4*)&imT[k][ng * 4];
    float4 s  = *(const float4*)(sp + k * CD + cg * 4);
    float4 a  = *(const float4*)(sa + k * CD + cg * 4);
    OUTER4(gr, er, s);
    OUTER4(ar, er, a);
    OUTER4(gi, ei, s);
    OUTER4(ai, ei, a);
  }
#pragma unroll
  for (int i = 0; i < 4; ++i) {
    int n = nb + ng * 4 + i;
    if (n < NPG) {
      float4 o;
      o.x = tanhf(fmaf(gr[i][0], ar[i][0], gi[i][0] * ai[i][0]));
      o.y = tanhf(fmaf(gr[i][1], ar[i][1], gi[i][1] * ai[i][1]));
      o.z = tanhf(fmaf(gr[i][2], ar[i][2], gi[i][2] * ai[i][2]));
      o.w = tanhf(fmaf(gr[i][3], ar[i][3], gi[i][3] * ai[i][3]));
      *(float4*)&gfeat[(gbase + n) * CD + cg * 4] = o;
    }
  }
}

// t1 = relu(h@W1a + EV@M1 + gfeat@W1c + b1); t1 aliases gfeat (tile-local RW)
__global__ void k_mlp1f(const float* __restrict__ h, const float* __restrict__ evecs,
                        const float* gfeat, const float* __restrict__ W1,
                        const float* __restrict__ M1, const float* __restrict__ b1,
                        float* t1) {
  const int BPG = 391;
  int b  = blockIdx.x / BPG;
  int nb = (blockIdx.x % BPG) * 32;
  int t = threadIdx.x, cg = t & 31, ng = t >> 5;
  __shared__ float hT[128][36];
  __shared__ float evT[128][36];
  __shared__ float gfT[128][36];
  size_t gbase = (size_t)b * NPG;
#pragma unroll
  for (int l = 0; l < 16; ++l) {
    int idx = l * 256 + t;
    int row = idx >> 7, col = idx & 127;
    bool ok = (nb + row) < NPG;
    size_t base = (gbase + nb + row) * (size_t)CD + col;
    hT[col][row]  = ok ? h[base] : 0.f;
    evT[col][row] = ok ? evecs[(gbase + nb + row) * (size_t)KD + col] : 0.f;
    gfT[col][row] = ok ? gfeat[base] : 0.f;
  }
  __syncthreads();
  const float* m1 = M1 + (size_t)b * KD * CD;
  float acc[4][4] = {};
#pragma unroll 8
  for (int k = 0; k < CD; ++k) {
    float4 e = *(const float4*)&hT[k][ng * 4];
    float4 w = *(const float4*)&W1[k * CD + cg * 4];
    OUTER4(acc, e, w);
  }
#pragma unroll 8
  for (int k = 0; k < KD; ++k) {
    float4 e = *(const float4*)&evT[k][ng * 4];
    float4 w = *(const float4*)(m1 + k * CD + cg * 4);
    OUTER4(acc, e, w);
  }
#pragma unroll 8
  for (int k = 0; k < CD; ++k) {
    float4 e = *(const float4*)&gfT[k][ng * 4];
    float4 w = *(const float4*)&W1[(2 * CD + k) * CD + cg * 4];
    OUTER4(acc, e, w);
  }
#pragma unroll
  for (int i = 0; i < 4; ++i) {
    int n = nb + ng * 4 + i;
    if (n < NPG) {
      float4 o;
      o.x = fmaxf(acc[i][0] + b1[cg * 4 + 0], 0.f);
      o.y = fmaxf(acc[i][1] + b1[cg * 4 + 1], 0.f);
      o.z = fmaxf(acc[i][2] + b1[cg * 4 + 2], 0.f);
      o.w = fmaxf(acc[i][3] + b1[cg * 4 + 3], 0.f);
      *(float4*)&t1[(gbase + n) * (size_t)CD + cg * 4] = o;
    }
  }
}

// h += t1 @ W2 + b2
__global__ void k_mlp2(const float* __restrict__ t1, const float* __restrict__ W2,
                       const float* __restrict__ b2, float* h) {
  int nb = blockIdx.x * 32;
  int t = threadIdx.x, cg = t & 31, ng = t >> 5;
  __shared__ float aT[CD][36];
#pragma unroll
  for (int l = 0; l < 16; ++l) {
    int idx = l * 256 + t;
    int row = idx >> 7, col = idx & 127;
    aT[col][row] = t1[(size_t)(nb + row) * CD + col];
  }
  __syncthreads();
  float acc[4][4] = {};
#pragma unroll 8
  for (int k = 0; k < CD; ++k) {
    float4 e = *(const float4*)&aT[k][ng * 4];
    float4 w = *(const float4*)&W2[k * CD + cg * 4];
    OUTER4(acc, e, w);
  }
#pragma unroll
  for (int i = 0; i < 4; ++i) {
    size_t n = nb + ng * 4 + i;
    float4* hp = (float4*)&h[n * CD + cg * 4];
    float4 hv = *hp;
    hv.x += acc[i][0] + b2[cg * 4 + 0];
    hv.y += acc[i][1] + b2[cg * 4 + 1];
    hv.z += acc[i][2] + b2[cg * 4 + 2];
    hv.w += acc[i][3] + b2[cg * 4 + 3];
    *hp = hv;
  }
}

// out = relu([h | gs[batch]] @ Wh1 + bh1) @ Wh2 + bh2 ; 4 nodes (waves) / block
__global__ void k_head(const float* __restrict__ h, const float* __restrict__ gs,
                       const int* __restrict__ batch,
                       const float* __restrict__ Wh1, const float* __restrict__ bh1,
                       const float* __restrict__ Wh2, const float* __restrict__ bh2,
                       float* __restrict__ out) {
  int w = threadIdx.x >> 6;
  int j = threadIdx.x & 63;
  int n = blockIdx.x * 4 + w;
  int b = batch[n];
  __shared__ float hs[4][128];
  __shared__ float zs[4][64];
  hs[w][j]      = h[(size_t)n * CD + j];
  hs[w][j + 64] = h[(size_t)n * CD + 64 + j];
  __syncthreads();
  float acc = bh1[j];
#pragma unroll 16
  for (int k = 0; k < CD; ++k) acc = fmaf(hs[w][k], Wh1[k * 64 + j], acc);
#pragma unroll
  for (int i = 0; i < GSDIM; ++i) acc = fmaf(gs[b * GSDIM + i], Wh1[(CD + i) * 64 + j], acc);
  zs[w][j] = fmaxf(acc, 0.f);
  __syncthreads();
  if (j < NCLF) {
    float o = bh2[j];
#pragma unroll 16
    for (int k = 0; k < 64; ++k) o = fmaf(zs[w][k], Wh2[k * NCLF + j], o);
    out[(size_t)n * NCLF + j] = o;
  }
}

extern "C" void kernel_launch(void* const* d_in, const int* in_sizes, int n_in,
                              void* d_out, int out_size, void* d_ws, size_t ws_size,
                              hipStream_t stream) {
  const float* x     = (const float*)d_in[0];
  const float* evals = (const float*)d_in[1];
  const float* evecs = (const float*)d_in[2];
  const float* mass  = (const float*)d_in[3];
  const float* gs    = (const float*)d_in[4];
  const int*   batch = (const int*)d_in[5];
  const int*   grows = (const int*)d_in[6];
  const int*   gcols = (const int*)d_in[7];
  const float* vre   = (const float*)d_in[8];
  const float* vim   = (const float*)d_in[9];
  const float* Wemb  = (const float*)d_in[11];
  const float* bemb  = (const float*)d_in[12];
  const float* tdiff = (const float*)d_in[13];
  const float* Agrad = (const float*)d_in[14];
  const float* W1    = (const float*)d_in[15];
  const float* b1    = (const float*)d_in[16];
  const float* W2    = (const float*)d_in[17];
  const float* b2    = (const float*)d_in[18];
  const float* Wh1   = (const float*)d_in[19];
  const float* bh1   = (const float*)d_in[20];
  const float* Wh2   = (const float*)d_in[21];
  const float* bh2   = (const float*)d_in[22];

  float* ws = (float*)d_ws;
  const size_t NC = (size_t)NNODES * CD;       // 12.8M floats
  const size_t NK = (size_t)NNODES * KD;
  float* h     = ws;                           // [N,C] fp32
  float* gfeat = ws + NC;                      // [N,C] fp32 (aliases t1)
  unsigned short* Gre16 = (unsigned short*)(ws + 2 * NC);   // [N,K] bf16
  unsigned short* Gim16 = Gre16 + NK;
  float* spec  = ws + 3 * NC;                  // [8,128,128]
  float* SA    = spec + (size_t)NGRAPH * KD * CD;
  float* M1    = SA   + (size_t)NGRAPH * KD * CD;
  float* A_T   = M1   + (size_t)NGRAPH * KD * CD;     // [4,128,128]
  int*   cnt    = (int*)(A_T + (size_t)NBLKS * CD * CD);    // [100352] ints (padded)
  int*   bucket = cnt + 100352;                             // [N*BCAP] ints (25.6MB)
  float* out   = (float*)d_out;

  k_embed<<<NNODES / 2, 256, 0, stream>>>(x, Wemb, bemb, h);
  k_transA<<<(NBLKS * CD * CD) / 256, 256, 0, stream>>>(Agrad, A_T);

  // once per launch: bucket edges by row, then gather -> bf16 GreEV/GimEV
  k_fill0<<<128, 256, 0, stream>>>((float4*)cnt, 100352 / 4);
  k_bucket_place<<<(NEDGE + 255) / 256, 256, 0, stream>>>(grows, cnt, bucket);
  k_gather_ev<<<NNODES / 4, 256, 0, stream>>>(cnt, bucket, gcols, vre, vim, evecs,
                                              Gre16, Gim16);

  for (int blk = 0; blk < NBLKS; ++blk) {
    const float* W1blk = W1 + (size_t)blk * 3 * CD * CD;
    k_fill0<<<128, 256, 0, stream>>>((float4*)spec, (int)(NGRAPH * KD * CD / 4));
    k_to_basis<<<NGRAPH * 4 * TBSPLIT, 256, 0, stream>>>(evecs, h, mass, spec);
    k_scale_spec<<<(NGRAPH * KD * CD) / 256, 256, 0, stream>>>(spec, evals, tdiff, blk);
    k_specA<<<NGRAPH * 4, 256, 0, stream>>>(spec, A_T + (size_t)blk * CD * CD, SA);
    k_specW1<<<NGRAPH * 4, 256, 0, stream>>>(spec, W1blk + (size_t)CD * CD, M1);
    k_gfeat2<<<NGRAPH * 391, 256, 0, stream>>>(Gre16, Gim16, spec, SA, gfeat);
    k_mlp1f<<<NGRAPH * 391, 256, 0, stream>>>(h, evecs, gfeat, W1blk, M1,
                                              b1 + blk * CD, gfeat);
    k_mlp2<<<NNODES / 32, 256, 0, stream>>>(gfeat, W2 + (size_t)blk * CD * CD,
                                            b2 + blk * CD, h);
  }
  k_head<<<NNODES / 4, 256, 0, stream>>>(h, gs, batch, Wh1, bh1, Wh2, bh2, out);
}

// Round 4
// 1046.540 us; speedup vs baseline: 13.7934x; 3.6794x over previous
//
#include <hip/hip_runtime.h>
#include <hip/hip_bf16.h>

#define NNODES 100000
#define NPG    12500
#define NGRAPH 8
#define KD     128
#define CD     128
#define INDIM  7
#define GSDIM  11
#define NBLKS  4
#define NCLF   5
#define NEDGE  800000
#define BCAP   64
#define NPGP   12800          // padded nodes per graph (25 * 512)
#define TBSPLIT 25            // to_basis split-n
#define TBCHUNK 512           // = NPGP / TBSPLIT, 16 k-steps of 32
#define NTILES  196           // ceil(12500/64)

typedef __attribute__((ext_vector_type(8))) short short8v;
typedef __attribute__((ext_vector_type(4))) float f32x4;
typedef unsigned short u16;

#define MFMA(acc, a, b) acc = __builtin_amdgcn_mfma_f32_16x16x32_bf16(a, b, acc, 0, 0, 0)

__device__ __forceinline__ u16 f2b(float f) {
  union { __hip_bfloat16 h; u16 u; } cv;
  cv.h = __float2bfloat16(f);
  return cv.u;
}

// ---------- LDS staging helpers (chunk layout: [rows][40] u16, 32 valid k) ----------
// 80-byte row pitch => frag b128 reads hit disjoint bank quads (<=2-way).

__device__ __forceinline__ void stage64_f32(u16* S, const float* src, int ld, int k0, int valid) {
  int t = threadIdx.x, row = t >> 2, kq = t & 3;
  alignas(16) u16 tmp[8] = {0, 0, 0, 0, 0, 0, 0, 0};
  if (row < valid) {
    const float* p = src + (size_t)row * ld + k0 + kq * 8;
    float4 f0 = *(const float4*)p, f1 = *(const float4*)(p + 4);
    tmp[0] = f2b(f0.x); tmp[1] = f2b(f0.y); tmp[2] = f2b(f0.z); tmp[3] = f2b(f0.w);
    tmp[4] = f2b(f1.x); tmp[5] = f2b(f1.y); tmp[6] = f2b(f1.z); tmp[7] = f2b(f1.w);
  }
  *(uint4*)&S[row * 40 + kq * 8] = *(uint4*)tmp;
}

__device__ __forceinline__ void stage64_b16(u16* S, const u16* src, int ld, int k0, int valid) {
  int t = threadIdx.x, row = t >> 2, kq = t & 3;
  uint4 v = make_uint4(0, 0, 0, 0);
  if (row < valid) v = *(const uint4*)(src + (size_t)row * ld + k0 + kq * 8);
  *(uint4*)&S[row * 40 + kq * 8] = v;
}

__device__ __forceinline__ void stage128_b16(u16* S, const u16* src, long ld, int k0) {
  int t = threadIdx.x, row = t >> 1, half = t & 1;
  const u16* p = src + (size_t)row * ld + k0 + half * 16;
  uint4 v0 = *(const uint4*)p, v1 = *(const uint4*)(p + 8);
  *(uint4*)&S[row * 40 + half * 16] = v0;
  *(uint4*)&S[row * 40 + half * 16 + 8] = v1;
}

__device__ __forceinline__ void stage128_f32(u16* S, const float* src, int ld, int k0) {
  int t = threadIdx.x, row = t >> 1, half = t & 1;
  const float* p = src + (size_t)row * ld + k0 + half * 16;
  float4 f0 = *(const float4*)p, f1 = *(const float4*)(p + 4);
  float4 f2 = *(const float4*)(p + 8), f3 = *(const float4*)(p + 12);
  alignas(16) u16 tmp[16];
  tmp[0] = f2b(f0.x); tmp[1] = f2b(f0.y); tmp[2]  = f2b(f0.z); tmp[3]  = f2b(f0.w);
  tmp[4] = f2b(f1.x); tmp[5] = f2b(f1.y); tmp[6]  = f2b(f1.z); tmp[7]  = f2b(f1.w);
  tmp[8] = f2b(f2.x); tmp[9] = f2b(f2.y); tmp[10] = f2b(f2.z); tmp[11] = f2b(f2.w);
  tmp[12] = f2b(f3.x); tmp[13] = f2b(f3.y); tmp[14] = f2b(f3.z); tmp[15] = f2b(f3.w);
  *(uint4*)&S[row * 40 + half * 16] = *(uint4*)&tmp[0];
  *(uint4*)&S[row * 40 + half * 16 + 8] = *(uint4*)&tmp[8];
}

__device__ __forceinline__ short8v frag(const u16* S, int row0, int l) {
  return *(const short8v*)&S[(row0 + (l & 15)) * 40 + (l >> 4) * 8];
}

// ---------------------- small utility kernels ----------------------

__global__ void k_fill0(float4* p, int n4) {
  int i = blockIdx.x * blockDim.x + threadIdx.x;
  int s = gridDim.x * blockDim.x;
  float4 z = make_float4(0.f, 0.f, 0.f, 0.f);
  for (; i < n4; i += s) p[i] = z;
}

__global__ void k_embed(const float* __restrict__ x, const float* __restrict__ W,
                        const float* __restrict__ bv, float* __restrict__ h) {
  int w = threadIdx.x >> 7;
  int c = threadIdx.x & 127;
  int n = blockIdx.x * 2 + w;
  __shared__ float xs[2][INDIM];
  if (c < INDIM) xs[w][c] = x[n * INDIM + c];
  __syncthreads();
  float acc = bv[c];
#pragma unroll
  for (int i = 0; i < INDIM; ++i) acc = fmaf(xs[w][i], W[i * CD + c], acc);
  h[(size_t)n * CD + c] = fmaxf(acc, 0.f);
}

__global__ void k_bucket_place(const int* __restrict__ rows, int* cnt, int* bucket) {
  int e = blockIdx.x * 256 + threadIdx.x;
  if (e >= NEDGE) return;
  int r = rows[e];
  int pos = atomicAdd(&cnt[r], 1);
  if (pos < BCAP) bucket[(size_t)r * BCAP + pos] = e;
}

__global__ void k_gather_ev(const int* __restrict__ cnt, const int* __restrict__ bucket,
                            const int* __restrict__ cols,
                            const float* __restrict__ vre, const float* __restrict__ vim,
                            const float* __restrict__ ev,
                            u16* __restrict__ gre, u16* __restrict__ gim) {
  int wv = threadIdx.x >> 6;
  int ln = threadIdx.x & 63;
  int r  = blockIdx.x * 4 + wv;
  if (r >= NNODES) return;
  int d = min(cnt[r], BCAP);
  const int* bk = bucket + (size_t)r * BCAP;
  float2 ra = make_float2(0.f, 0.f), ia = make_float2(0.f, 0.f);
  for (int i = 0; i < d; ++i) {
    int e = bk[i];
    float a = vre[e], b = vim[e];
    float2 v = *(const float2*)&ev[(size_t)cols[e] * KD + ln * 2];
    ra.x = fmaf(a, v.x, ra.x); ra.y = fmaf(a, v.y, ra.y);
    ia.x = fmaf(b, v.x, ia.x); ia.y = fmaf(b, v.y, ia.y);
  }
  ushort2 ro, io;
  ro.x = f2b(ra.x); ro.y = f2b(ra.y);
  io.x = f2b(ia.x); io.y = f2b(ia.y);
  *(ushort2*)&gre[(size_t)r * KD + ln * 2] = ro;
  *(ushort2*)&gim[(size_t)r * KD + ln * 2] = io;
}

// Transposed bf16 weights: W*T[c][j] = W[j][c]
__global__ void k_prep_w(const float* __restrict__ W1, const float* __restrict__ W2,
                         u16* W1aT, u16* W1bT, u16* W1cT, u16* W2T) {
  int idx = blockIdx.x * 256 + threadIdx.x;      // 4 * 4 * 16384
  int blk = idx >> 16, rem = idx & 65535;
  int mat = rem >> 14, e = rem & 16383;
  int j = e >> 7, c = e & 127;
  float v;
  u16* dst;
  if (mat < 3) {
    v = W1[(size_t)blk * 3 * 16384 + (size_t)mat * 16384 + e];
    dst = (mat == 0) ? W1aT : (mat == 1 ? W1bT : W1cT);
  } else {
    v = W2[(size_t)blk * 16384 + e];
    dst = W2T;
  }
  dst[(size_t)blk * 16384 + c * 128 + j] = f2b(v);
}

// dst[b][k][n_padded] = src[gbase+n][k] (* mass) as bf16; zero padding to NPGP
__global__ void k_transpose_nk(const float* __restrict__ src, const float* __restrict__ mass,
                               int useMass, u16* __restrict__ dst) {
  int b = blockIdx.x / 200, tile = blockIdx.x % 200;
  int n0 = tile * 64;
  size_t gbase = (size_t)b * NPG;
  int t = threadIdx.x;
  __shared__ float ld[64][132];
  int row0 = t >> 5, c4 = t & 31;
#pragma unroll
  for (int it = 0; it < 8; ++it) {
    int r = it * 8 + row0;
    int gn = n0 + r;
    float4 v = make_float4(0.f, 0.f, 0.f, 0.f);
    if (gn < NPG) {
      v = *(const float4*)&src[(gbase + gn) * CD + c4 * 4];
      if (useMass) {
        float m = mass[gbase + gn];
        v.x *= m; v.y *= m; v.z *= m; v.w *= m;
      }
    }
    *(float4*)&ld[r][c4 * 4] = v;
  }
  __syncthreads();
  int crow = t >> 1, half = t & 1;
  alignas(16) u16 tmp[8];
#pragma unroll
  for (int q = 0; q < 4; ++q) {
    int nb = half * 32 + q * 8;
#pragma unroll
    for (int i = 0; i < 8; ++i) tmp[i] = f2b(ld[nb + i][crow]);
    *(uint4*)&dst[((size_t)(b * 128 + crow)) * NPGP + n0 + nb] = *(uint4*)tmp;
  }
}

// ---------------------- MFMA kernels ----------------------

// partials[(b*TBSPLIT+s)][k][c] = sum_{n in chunk} evT[b][k][n] * hmT[b][c][n]
__global__ __launch_bounds__(256) void k_tobasis(const u16* __restrict__ evT,
                                                 const u16* __restrict__ hmT,
                                                 float* __restrict__ partials) {
  int b = blockIdx.x / TBSPLIT, s = blockIdx.x % TBSPLIT;
  int t = threadIdx.x, w = t >> 6, l = t & 63;
  __shared__ u16 As[128 * 40];
  __shared__ u16 Bs[128 * 40];
  f32x4 acc[2][8];
  f32x4 z = {0.f, 0.f, 0.f, 0.f};
#pragma unroll
  for (int mi = 0; mi < 2; ++mi)
#pragma unroll
    for (int j = 0; j < 8; ++j) acc[mi][j] = z;
  const u16* ae = evT + (size_t)b * 128 * NPGP + s * TBCHUNK;
  const u16* bh = hmT + (size_t)b * 128 * NPGP + s * TBCHUNK;
  for (int ks = 0; ks < TBCHUNK / 32; ++ks) {
    stage128_b16(As, ae, NPGP, ks * 32);
    stage128_b16(Bs, bh, NPGP, ks * 32);
    __syncthreads();
    short8v a0 = frag(As, w * 32, l);
    short8v a1 = frag(As, w * 32 + 16, l);
#pragma unroll
    for (int j = 0; j < 8; ++j) {
      short8v bj = frag(Bs, j * 16, l);
      MFMA(acc[0][j], a0, bj);
      MFMA(acc[1][j], a1, bj);
    }
    __syncthreads();
  }
  float* op = partials + (size_t)(b * TBSPLIT + s) * 16384;
#pragma unroll
  for (int mi = 0; mi < 2; ++mi)
#pragma unroll
    for (int j = 0; j < 8; ++j)
#pragma unroll
      for (int i = 0; i < 4; ++i) {
        int krow = w * 32 + mi * 16 + (l >> 4) * 4 + i;
        int c = j * 16 + (l & 15);
        op[krow * 128 + c] = acc[mi][j][i];
      }
}

// spec[b][k][c] = scale(sum_s partials); specT16[b][c][k] = bf16(spec)
__global__ void k_reduce_scale_t(const float* __restrict__ partials,
                                 const float* __restrict__ evals,
                                 const float* __restrict__ td,
                                 float* __restrict__ spec, u16* __restrict__ specT) {
  int b = blockIdx.x >> 6;
  int idx = (blockIdx.x & 63) * 256 + threadIdx.x;
  int k = idx >> 7, c = idx & 127;
  float s = 0.f;
#pragma unroll
  for (int sp = 0; sp < TBSPLIT; ++sp)
    s += partials[(size_t)(b * TBSPLIT + sp) * 16384 + idx];
  float tm = fmaxf(fabsf(td[c]), 1e-8f);
  s *= expf(-evals[b * KD + k] * tm);
  spec[(size_t)b * 16384 + idx] = s;
  specT[(size_t)b * 16384 + c * 128 + k] = f2b(s);
}

// job0: SAT16[b][c][k] = sum_j Agrad[c][j]*spec[b][k][j]
// job1: M1T16[b][c][k] = sum_j W1bT[c][j]*spec[b][k][j]
__global__ __launch_bounds__(256) void k_smallT(const float* __restrict__ Agrad_blk,
                                                const u16* __restrict__ W1bT_blk,
                                                const float* __restrict__ spec,
                                                u16* __restrict__ SAT, u16* __restrict__ M1T) {
  int b = blockIdx.x & 7, job = blockIdx.x >> 3;
  int t = threadIdx.x, w = t >> 6, l = t & 63;
  __shared__ u16 As[128 * 40];
  __shared__ u16 Bs[128 * 40];
  f32x4 acc[2][8];
  f32x4 z = {0.f, 0.f, 0.f, 0.f};
#pragma unroll
  for (int mi = 0; mi < 2; ++mi)
#pragma unroll
    for (int j = 0; j < 8; ++j) acc[mi][j] = z;
  for (int ks = 0; ks < 4; ++ks) {
    if (job == 0) stage128_f32(As, Agrad_blk, 128, ks * 32);
    else          stage128_b16(As, W1bT_blk, 128, ks * 32);
    stage128_f32(Bs, spec + (size_t)b * 16384, 128, ks * 32);
    __syncthreads();
    short8v a0 = frag(As, w * 32, l);
    short8v a1 = frag(As, w * 32 + 16, l);
#pragma unroll
    for (int j = 0; j < 8; ++j) {
      short8v bj = frag(Bs, j * 16, l);
      MFMA(acc[0][j], a0, bj);
      MFMA(acc[1][j], a1, bj);
    }
    __syncthreads();
  }
  u16* out = (job == 0 ? SAT : M1T) + (size_t)b * 16384;
#pragma unroll
  for (int mi = 0; mi < 2; ++mi)
#pragma unroll
    for (int j = 0; j < 8; ++j)
#pragma unroll
      for (int i = 0; i < 4; ++i)
        out[(w * 32 + mi * 16 + (l >> 4) * 4 + i) * 128 + j * 16 + (l & 15)] =
            f2b(acc[mi][j][i]);
}

// gf16 = tanh((Gre@spec')*(Gre@SA) + (Gim@spec')*(Gim@SA))   [bf16 out]
__global__ __launch_bounds__(256) void k_gfeat(const u16* __restrict__ Gre,
                                               const u16* __restrict__ Gim,
                                               const u16* __restrict__ specT,
                                               const u16* __restrict__ SAT,
                                               u16* __restrict__ gf) {
  int b = blockIdx.x / NTILES, tile = blockIdx.x % NTILES;
  int n0 = tile * 64;
  size_t gbase = (size_t)b * NPG;
  int t = threadIdx.x, w = t >> 6, l = t & 63;
  int r0 = (w & 1) * 32, c0 = (w >> 1) * 64;
  __shared__ u16 Sr[64 * 40];
  __shared__ u16 Si[64 * 40];
  __shared__ u16 Bs[128 * 40];
  __shared__ u16 Ba[128 * 40];
  f32x4 aGR[2][4], aAR[2][4], aGI[2][4], aAI[2][4];
  f32x4 z = {0.f, 0.f, 0.f, 0.f};
#pragma unroll
  for (int mi = 0; mi < 2; ++mi)
#pragma unroll
    for (int j = 0; j < 4; ++j) { aGR[mi][j] = z; aAR[mi][j] = z; aGI[mi][j] = z; aAI[mi][j] = z; }
  int valid = min(64, NPG - n0);
  const u16* gre = Gre + (gbase + n0) * KD;
  const u16* gim = Gim + (gbase + n0) * KD;
  for (int ks = 0; ks < 4; ++ks) {
    stage64_b16(Sr, gre, KD, ks * 32, valid);
    stage64_b16(Si, gim, KD, ks * 32, valid);
    stage128_b16(Bs, specT + (size_t)b * 16384, 128, ks * 32);
    stage128_b16(Ba, SAT + (size_t)b * 16384, 128, ks * 32);
    __syncthreads();
    short8v fr0 = frag(Sr, r0, l), fr1 = frag(Sr, r0 + 16, l);
    short8v fi0 = frag(Si, r0, l), fi1 = frag(Si, r0 + 16, l);
#pragma unroll
    for (int j = 0; j < 4; ++j) {
      short8v bs = frag(Bs, c0 + j * 16, l);
      short8v ba = frag(Ba, c0 + j * 16, l);
      MFMA(aGR[0][j], fr0, bs); MFMA(aGR[1][j], fr1, bs);
      MFMA(aAR[0][j], fr0, ba); MFMA(aAR[1][j], fr1, ba);
      MFMA(aGI[0][j], fi0, bs); MFMA(aGI[1][j], fi1, bs);
      MFMA(aAI[0][j], fi0, ba); MFMA(aAI[1][j], fi1, ba);
    }
    __syncthreads();
  }
#pragma unroll
  for (int mi = 0; mi < 2; ++mi)
#pragma unroll
    for (int j = 0; j < 4; ++j) {
      int c = c0 + j * 16 + (l & 15);
#pragma unroll
      for (int i = 0; i < 4; ++i) {
        int n = n0 + r0 + mi * 16 + (l >> 4) * 4 + i;
        if (n < NPG) {
          float v = tanhf(fmaf(aGR[mi][j][i], aAR[mi][j][i], aGI[mi][j][i] * aAI[mi][j][i]));
          gf[(gbase + n) * CD + c] = f2b(v);
        }
      }
    }
}

// t1 = relu(h@W1a + ev@M1 + gf@W1c + b1)   [bf16 out]
__global__ __launch_bounds__(256) void k_mlp1(const float* __restrict__ h,
                                              const float* __restrict__ ev,
                                              const u16* __restrict__ gf,
                                              const u16* __restrict__ W1aT,
                                              const u16* __restrict__ M1T,
                                              const u16* __restrict__ W1cT,
                                              const float* __restrict__ b1,
                                              u16* __restrict__ t1) {
  int b = blockIdx.x / NTILES, tile = blockIdx.x % NTILES;
  int n0 = tile * 64;
  size_t gbase = (size_t)b * NPG;
  int t = threadIdx.x, w = t >> 6, l = t & 63;
  __shared__ u16 As[64 * 40];
  __shared__ u16 Bs[128 * 40];
  f32x4 acc[8];
  f32x4 z = {0.f, 0.f, 0.f, 0.f};
#pragma unroll
  for (int j = 0; j < 8; ++j) acc[j] = z;
  int valid = min(64, NPG - n0);
  for (int seg = 0; seg < 3; ++seg) {
    const u16* bt = (seg == 0) ? W1aT : (seg == 1 ? M1T + (size_t)b * 16384 : W1cT);
    for (int ks = 0; ks < 4; ++ks) {
      if (seg == 0)      stage64_f32(As, h + (gbase + n0) * CD, CD, ks * 32, valid);
      else if (seg == 1) stage64_f32(As, ev + (gbase + n0) * KD, KD, ks * 32, valid);
      else               stage64_b16(As, gf + (gbase + n0) * CD, CD, ks * 32, valid);
      stage128_b16(Bs, bt, 128, ks * 32);
      __syncthreads();
      short8v a = frag(As, w * 16, l);
#pragma unroll
      for (int j = 0; j < 8; ++j) MFMA(acc[j], a, frag(Bs, j * 16, l));
      __syncthreads();
    }
  }
#pragma unroll
  for (int j = 0; j < 8; ++j) {
    int c = j * 16 + (l & 15);
    float bias = b1[c];
#pragma unroll
    for (int i = 0; i < 4; ++i) {
      int n = n0 + w * 16 + (l >> 4) * 4 + i;
      if (n < NPG) t1[(gbase + n) * CD + c] = f2b(fmaxf(acc[j][i] + bias, 0.f));
    }
  }
}

// h += t1 @ W2 + b2
__global__ __launch_bounds__(256) void k_mlp2(const u16* __restrict__ t1,
                                              const u16* __restrict__ W2T,
                                              const float* __restrict__ b2,
                                              float* __restrict__ h) {
  int b = blockIdx.x / NTILES, tile = blockIdx.x % NTILES;
  int n0 = tile * 64;
  size_t gbase = (size_t)b * NPG;
  int t = threadIdx.x, w = t >> 6, l = t & 63;
  __shared__ u16 As[64 * 40];
  __shared__ u16 Bs[128 * 40];
  f32x4 acc[8];
  f32x4 z = {0.f, 0.f, 0.f, 0.f};
#pragma unroll
  for (int j = 0; j < 8; ++j) acc[j] = z;
  int valid = min(64, NPG - n0);
  for (int ks = 0; ks < 4; ++ks) {
    stage64_b16(As, t1 + (gbase + n0) * CD, CD, ks * 32, valid);
    stage128_b16(Bs, W2T, 128, ks * 32);
    __syncthreads();
    short8v a = frag(As, w * 16, l);
#pragma unroll
    for (int j = 0; j < 8; ++j) MFMA(acc[j], a, frag(Bs, j * 16, l));
    __syncthreads();
  }
#pragma unroll
  for (int j = 0; j < 8; ++j) {
    int c = j * 16 + (l & 15);
    float bias = b2[c];
#pragma unroll
    for (int i = 0; i < 4; ++i) {
      int n = n0 + w * 16 + (l >> 4) * 4 + i;
      if (n < NPG) {
        float* hp = &h[(gbase + n) * CD + c];
        *hp += acc[j][i] + bias;
      }
    }
  }
}

// out = relu([h | gs[batch]] @ Wh1 + bh1) @ Wh2 + bh2
__global__ void k_head(const float* __restrict__ h, const float* __restrict__ gs,
                       const int* __restrict__ batch,
                       const float* __restrict__ Wh1, const float* __restrict__ bh1,
                       const float* __restrict__ Wh2, const float* __restrict__ bh2,
                       float* __restrict__ out) {
  int w = threadIdx.x >> 6;
  int j = threadIdx.x & 63;
  int n = blockIdx.x * 4 + w;
  int b = batch[n];
  __shared__ float hs[4][128];
  __shared__ float zs[4][64];
  hs[w][j]      = h[(size_t)n * CD + j];
  hs[w][j + 64] = h[(size_t)n * CD + 64 + j];
  __syncthreads();
  float acc = bh1[j];
#pragma unroll 16
  for (int k = 0; k < CD; ++k) acc = fmaf(hs[w][k], Wh1[k * 64 + j], acc);
#pragma unroll
  for (int i = 0; i < GSDIM; ++i) acc = fmaf(gs[b * GSDIM + i], Wh1[(CD + i) * 64 + j], acc);
  zs[w][j] = fmaxf(acc, 0.f);
  __syncthreads();
  if (j < NCLF) {
    float o = bh2[j];
#pragma unroll 16
    for (int k = 0; k < 64; ++k) o = fmaf(zs[w][k], Wh2[k * NCLF + j], o);
    out[(size_t)n * NCLF + j] = o;
  }
}

extern "C" void kernel_launch(void* const* d_in, const int* in_sizes, int n_in,
                              void* d_out, int out_size, void* d_ws, size_t ws_size,
                              hipStream_t stream) {
  const float* x     = (const float*)d_in[0];
  const float* evals = (const float*)d_in[1];
  const float* evecs = (const float*)d_in[2];
  const float* mass  = (const float*)d_in[3];
  const float* gs    = (const float*)d_in[4];
  const int*   batch = (const int*)d_in[5];
  const int*   grows = (const int*)d_in[6];
  const int*   gcols = (const int*)d_in[7];
  const float* vre   = (const float*)d_in[8];
  const float* vim   = (const float*)d_in[9];
  const float* Wemb  = (const float*)d_in[11];
  const float* bemb  = (const float*)d_in[12];
  const float* tdiff = (const float*)d_in[13];
  const float* Agrad = (const float*)d_in[14];
  const float* W1    = (const float*)d_in[15];
  const float* b1    = (const float*)d_in[16];
  const float* W2    = (const float*)d_in[17];
  const float* b2    = (const float*)d_in[18];
  const float* Wh1   = (const float*)d_in[19];
  const float* bh1   = (const float*)d_in[20];
  const float* Wh2   = (const float*)d_in[21];
  const float* bh2   = (const float*)d_in[22];

  // ---- workspace layout (byte offsets, 256B aligned blocks) ----
  char* base = (char*)d_ws;
  size_t off = 0;
  auto alloc = [&](size_t bytes) -> void* {
    void* p = base + off;
    off += (bytes + 255) & ~(size_t)255;
    return p;
  };
  float* h      = (float*)alloc((size_t)NNODES * CD * 4);              // 51.2 MB
  u16*   evT16  = (u16*)alloc((size_t)NGRAPH * 128 * NPGP * 2);        // 26.2 MB
  u16*   hmT    = (u16*)alloc((size_t)NGRAPH * 128 * NPGP * 2);        // 26.2 MB (t1 aliases)
  u16*   t1     = hmT;
  u16*   Gre16  = (u16*)alloc((size_t)NNODES * KD * 2);                // 25.6 MB
  u16*   Gim16  = (u16*)alloc((size_t)NNODES * KD * 2);                // 25.6 MB
  float* spec   = (float*)alloc((size_t)NGRAPH * 16384 * 4);
  u16*   specT16 = (u16*)alloc((size_t)NGRAPH * 16384 * 2);
  u16*   SAT16  = (u16*)alloc((size_t)NGRAPH * 16384 * 2);
  u16*   M1T16  = (u16*)alloc((size_t)NGRAPH * 16384 * 2);
  u16*   W1aT16 = (u16*)alloc((size_t)NBLKS * 16384 * 2);
  u16*   W1bT16 = (u16*)alloc((size_t)NBLKS * 16384 * 2);
  u16*   W1cT16 = (u16*)alloc((size_t)NBLKS * 16384 * 2);
  u16*   W2T16  = (u16*)alloc((size_t)NBLKS * 16384 * 2);
  int*   cnt    = (int*)alloc(100352 * 4);
  // R region: bucket (pre-loop) / partials (early-iter) / gf16 (late-iter) share
  void*  R      = alloc((size_t)NNODES * BCAP * 4);                    // 25.6 MB
  int*   bucket = (int*)R;
  float* partials = (float*)R;
  u16*   gf16   = (u16*)R;
  float* out    = (float*)d_out;

  // ---- once per launch ----
  k_embed<<<NNODES / 2, 256, 0, stream>>>(x, Wemb, bemb, h);
  k_fill0<<<98, 256, 0, stream>>>((float4*)cnt, 100352 / 4);
  k_bucket_place<<<(NEDGE + 255) / 256, 256, 0, stream>>>(grows, cnt, bucket);
  k_gather_ev<<<NNODES / 4, 256, 0, stream>>>(cnt, bucket, gcols, vre, vim, evecs,
                                              Gre16, Gim16);
  k_prep_w<<<1024, 256, 0, stream>>>(W1, W2, W1aT16, W1bT16, W1cT16, W2T16);
  k_transpose_nk<<<NGRAPH * 200, 256, 0, stream>>>(evecs, mass, 0, evT16);

  for (int blk = 0; blk < NBLKS; ++blk) {
    k_transpose_nk<<<NGRAPH * 200, 256, 0, stream>>>(h, mass, 1, hmT);
    k_tobasis<<<NGRAPH * TBSPLIT, 256, 0, stream>>>(evT16, hmT, partials);
    k_reduce_scale_t<<<NGRAPH * 64, 256, 0, stream>>>(partials, evals, tdiff + blk * CD,
                                                      spec, specT16);
    k_smallT<<<16, 256, 0, stream>>>(Agrad + (size_t)blk * 16384,
                                     W1bT16 + (size_t)blk * 16384, spec, SAT16, M1T16);
    k_gfeat<<<NGRAPH * NTILES, 256, 0, stream>>>(Gre16, Gim16, specT16, SAT16, gf16);
    k_mlp1<<<NGRAPH * NTILES, 256, 0, stream>>>(h, evecs, gf16,
                                                W1aT16 + (size_t)blk * 16384, M1T16,
                                                W1cT16 + (size_t)blk * 16384,
                                                b1 + blk * CD, t1);
    k_mlp2<<<NGRAPH * NTILES, 256, 0, stream>>>(t1, W2T16 + (size_t)blk * 16384,
                                                b2 + blk * CD, h);
  }
  k_head<<<NNODES / 4, 256, 0, stream>>>(h, gs, batch, Wh1, bh1, Wh2, bh2, out);
}